// Round 5
// baseline (354.021 us; speedup 1.0000x reference)
//
#include <hip/hip_runtime.h>

// LSTMP via MFMA, fp32 I/O, f16 compute, fp32 accumulate.
// B=4096, T=512, IN=4, HID=64, PROJ=52. Grid 256 x 512thr (8 waves, 2/SIMD), 16 batch/block.
//
// Round-5 structure (round 4 + hid split across 8 waves for latency hiding):
//  - wave w owns hid [8w, 8w+8): gate A-tile has the 8 valid rows permuted to
//    C rows m = quad*4 + {0,1} (r=2,3 rows zero) -> 2 hid/lane, 20 trans/wave
//    (half of round 4) while per-SIMD trans issue stays constant (2 waves).
//  - d exchange: one ds_write_b32 per lane (hid = 8w + quad*2 + {0,1}),
//    double-buffered, ONE barrier/step.
//  - projection computed redundantly by every wave (8 MFMA) with row-permuted
//    A-fragments; h' = C layout = next gate B-frag layout -> h never in LDS.
//  - log2e folded into weights (i,f,o x L; g x 2L; c kept as c' = 2L*c);
//    sigmoid/tanh via raw v_exp_f32 (exp2) + v_rcp_f32.
// Numerics identical to round 4 (same rounding path per hid) -> absmax ~9.8e-4.

#define T_STEPS 512
#define HID 64
#define NPROJ 52
#define NBATCH 16
#define NWAVES 8
#define ROWB 136            // LDS d-row stride bytes (128B data + 8B pad); conflicts measured 0
#define LOG2E 1.44269504088896340736f

typedef _Float16 half8 __attribute__((ext_vector_type(8)));
typedef float f32x4 __attribute__((ext_vector_type(4)));

__device__ __forceinline__ float exp2_f(float x) {
#if __has_builtin(__builtin_amdgcn_exp2f)
    return __builtin_amdgcn_exp2f(x);
#else
    return exp2f(x);
#endif
}
__device__ __forceinline__ float rcp_f(float x) {
    return __builtin_amdgcn_rcpf(x);
}

__global__ __launch_bounds__(512, 2)
void lstmp_kernel(const float* __restrict__ x,      // [4096][512][4]
                  const float* __restrict__ Wih,    // [256][4]
                  const float* __restrict__ Whh,    // [256][52]
                  const float* __restrict__ bih,    // [256]
                  const float* __restrict__ bhh,    // [256]
                  const float* __restrict__ Whr,    // [52][64]
                  float* __restrict__ out)          // [4096][52]
{
    __shared__ unsigned long long dlds[2 * NBATCH * ROWB / 8]; // double-buffered d

    const int lane = threadIdx.x & 63;
    const int wave = threadIdx.x >> 6;           // 0..7
    const int quad = lane >> 4;
    const int col  = lane & 15;

    // ---- gate A-fragments, log2e-folded, row-permuted (one-time) ----
    // Tile row m valid iff (m&3)<2; then hid = 8*wave + (m>>2)*2 + (m&3).
    // A[m=col][k=ch*32+quad*8+j].
    half8 aG[4][2];
    const bool mvalid = (col & 3) < 2;
    const int hidA = 8 * wave + (col >> 2) * 2 + (col & 3);   // valid only if mvalid
#pragma unroll
    for (int g = 0; g < 4; ++g) {
        const float scale = (g == 2) ? (2.0f * LOG2E) : LOG2E;  // g-gate: tanh needs exp(2x)
        const int row = g * HID + hidA;
#pragma unroll
        for (int ch = 0; ch < 2; ++ch) {
#pragma unroll
            for (int j = 0; j < 8; ++j) {
                const int k = ch * 32 + quad * 8 + j;
                float v = 0.0f;
                if (mvalid) {
                    if (k < NPROJ)      v = Whh[row * NPROJ + k];
                    else if (k < 56)    v = Wih[row * 4 + (k - NPROJ)];
                    else if (k == 56)   v = bih[row] + bhh[row];
                    else                v = 0.0f;
                }
                aG[g][ch][j] = (_Float16)(v * scale);
            }
        }
    }

    // ---- proj A-fragments, row-permuted tiles (one-time, same as round 4) ----
    // tile tt, within-tile row m -> proj row p = (tt>>1)*32 + (m>>2)*8 + (tt&1)*4 + (m&3)
    half8 aP[4][2];
#pragma unroll
    for (int tt = 0; tt < 4; ++tt) {
        const int p = ((tt >> 1) * 32) + ((col >> 2) * 8) + ((tt & 1) * 4) + (col & 3);
#pragma unroll
        for (int ch = 0; ch < 2; ++ch) {
#pragma unroll
            for (int j = 0; j < 8; ++j) {
                const int k = ch * 32 + quad * 8 + j;
                aP[tt][ch][j] = (_Float16)((p < NPROJ) ? Whr[p * HID + k] : 0.0f);
            }
        }
    }

    // ---- x registers (col = batch; redundant across waves, L1-served) ----
    const float4* xp = (const float4*)x + (size_t)blockIdx.x * NBATCH * T_STEPS;
    const float4 x0 = xp[(size_t)col * T_STEPS + 0];
    float4 xv = xp[(size_t)col * T_STEPS + 1];   // holds x(t+1) during iteration t

    // ---- initial gate B-frags (t=0): h=0, x(0), bias-one ----
    half8 b0, b1;
#pragma unroll
    for (int j = 0; j < 8; ++j) { b0[j] = (_Float16)0.0f; b1[j] = (_Float16)0.0f; }
    if (quad == 2) {             // k=52..55 = x
        b1[4] = (_Float16)x0.x; b1[5] = (_Float16)x0.y;
        b1[6] = (_Float16)x0.z; b1[7] = (_Float16)x0.w;
    }
    if (quad == 3) {             // k=56 = 1.0 (bias column)
        b1[0] = (_Float16)1.0f;
    }

    float cacc[2] = {0.0f, 0.0f};   // c' = 2L*c for hid = 8w + quad*2 + r, r in {0,1}
    f32x4 hp[4];                    // proj C-results (permuted layout)

    const int dwoff = col * ROWB + (8 * wave + quad * 2) * 2;  // d write byte offset (b32)
    const int drbase = col * ROWB + quad * 16;                 // d read base (+ch*64)

#pragma unroll 1
    for (int t = 0; t < T_STEPS; ++t) {
        // ---- gates: 8 MFMA, K=64 (rows r=2,3 are zero-padded -> ignored) ----
        f32x4 ai = {0.f,0.f,0.f,0.f}, af_ = {0.f,0.f,0.f,0.f};
        f32x4 ag_ = {0.f,0.f,0.f,0.f}, ao_ = {0.f,0.f,0.f,0.f};
        ai  = __builtin_amdgcn_mfma_f32_16x16x32_f16(aG[0][0], b0, ai,  0, 0, 0);
        af_ = __builtin_amdgcn_mfma_f32_16x16x32_f16(aG[1][0], b0, af_, 0, 0, 0);
        ag_ = __builtin_amdgcn_mfma_f32_16x16x32_f16(aG[2][0], b0, ag_, 0, 0, 0);
        ao_ = __builtin_amdgcn_mfma_f32_16x16x32_f16(aG[3][0], b0, ao_, 0, 0, 0);
        ai  = __builtin_amdgcn_mfma_f32_16x16x32_f16(aG[0][1], b1, ai,  0, 0, 0);
        af_ = __builtin_amdgcn_mfma_f32_16x16x32_f16(aG[1][1], b1, af_, 0, 0, 0);
        ag_ = __builtin_amdgcn_mfma_f32_16x16x32_f16(aG[2][1], b1, ag_, 0, 0, 0);
        ao_ = __builtin_amdgcn_mfma_f32_16x16x32_f16(aG[3][1], b1, ao_, 0, 0, 0);

        // ---- activations for r in {0,1} only (2 hid/lane; 20 trans/wave) ----
        char* dbuf = (char*)dlds + (t & 1) * (NBATCH * ROWB);
        union { _Float16 h[2]; unsigned w; } du;
#pragma unroll
        for (int r = 0; r < 2; ++r) {
            const float iv = rcp_f(1.0f + exp2_f(-ai[r]));                       // sigmoid
            const float fv = rcp_f(1.0f + exp2_f(-af_[r]));
            const float ov = rcp_f(1.0f + exp2_f(-ao_[r]));
            const float gs = fmaf(-4.0f * LOG2E, rcp_f(1.0f + exp2_f(ag_[r])),
                                  2.0f * LOG2E);                                 // 2L*tanh(g)
            const float cn = fmaf(fv, cacc[r], iv * gs);                         // c' = 2L*c
            cacc[r] = cn;
            const float th = fmaf(-2.0f, rcp_f(1.0f + exp2_f(cn)), 1.0f);        // tanh(c)
            du.h[r] = (_Float16)(ov * th);                                       // RTNE
        }
        *(unsigned*)(dbuf + dwoff) = du.w;   // hid = 8w + quad*2 + {0,1}
        __syncthreads();                     // the ONLY barrier per step

        // ---- d B-frags from LDS ----
        half8 bd0, bd1;
        {
            const char* p0 = dbuf + drbase;
            union { unsigned long long q[2]; half8 h; } u0, u1;
            u0.q[0] = *(const unsigned long long*)(p0);
            u0.q[1] = *(const unsigned long long*)(p0 + 8);
            u1.q[0] = *(const unsigned long long*)(p0 + 64);
            u1.q[1] = *(const unsigned long long*)(p0 + 72);
            bd0 = u0.h; bd1 = u1.h;
        }

        // ---- projection: 8 MFMA, redundant per wave, permuted tiles ----
#pragma unroll
        for (int tt = 0; tt < 4; ++tt) {
            f32x4 acc = {0.f, 0.f, 0.f, 0.f};
            acc = __builtin_amdgcn_mfma_f32_16x16x32_f16(aP[tt][0], bd0, acc, 0, 0, 0);
            acc = __builtin_amdgcn_mfma_f32_16x16x32_f16(aP[tt][1], bd1, acc, 0, 0, 0);
            hp[tt] = acc;
        }

        // ---- build next-step gate B-frags in-register (h' = permuted C layout) ----
#pragma unroll
        for (int j = 0; j < 4; ++j) {
            b0[j]     = (_Float16)hp[0][j];   // k = quad*8 + j
            b0[4 + j] = (_Float16)hp[1][j];   // k = quad*8 + 4 + j
            b1[j]     = (_Float16)hp[2][j];   // k = 32 + quad*8 + j
            b1[4 + j] = (_Float16)hp[3][j];   // k = 32 + quad*8 + 4 + j
        }
        if (quad == 2) {                      // k=52..55 <- x(t+1)  (A rows 52..55 zeroed)
            b1[4] = (_Float16)xv.x; b1[5] = (_Float16)xv.y;
            b1[6] = (_Float16)xv.z; b1[7] = (_Float16)xv.w;
        }
        if (quad == 3) {                      // k=56 <- 1.0 (A rows 57..63 zeroed)
            b1[0] = (_Float16)1.0f;
        }

        // prefetch x(t+2)
        const int tn = (t + 2 < T_STEPS) ? (t + 2) : (T_STEPS - 1);
        xv = xp[(size_t)col * T_STEPS + tn];
    }

    // ---- epilogue: every wave holds full h_T (fp32, permuted C layout); wave 0 writes ----
    if (wave == 0) {
        const size_t bg = (size_t)blockIdx.x * NBATCH + col;
        float* o = out + bg * NPROJ;
#pragma unroll
        for (int tt = 0; tt < 4; ++tt) {
            const int pb = ((tt >> 1) * 32) + (quad * 8) + ((tt & 1) * 4);
#pragma unroll
            for (int r = 0; r < 4; ++r) {
                const int p = pb + r;
                if (p < NPROJ) o[p] = hp[tt][r];
            }
        }
    }
}

extern "C" void kernel_launch(void* const* d_in, const int* in_sizes, int n_in,
                              void* d_out, int out_size, void* d_ws, size_t ws_size,
                              hipStream_t stream) {
    const float* x   = (const float*)d_in[0];
    const float* Wih = (const float*)d_in[1];
    const float* Whh = (const float*)d_in[2];
    const float* bih = (const float*)d_in[3];
    const float* bhh = (const float*)d_in[4];
    const float* Whr = (const float*)d_in[5];
    float* out = (float*)d_out;

    dim3 grid(4096 / NBATCH);        // 256 blocks, 1 per CU
    dim3 block(NWAVES * 64);         // 512 threads = 8 waves = 2 waves/SIMD
    lstmp_kernel<<<grid, block, 0, stream>>>(x, Wih, Whh, bih, bhh, Whr, out);
}